// Round 9
// baseline (163.193 us; speedup 1.0000x reference)
//
#include <hip/hip_runtime.h>

#define COLS 117
#define NOUT1 20
#define ROWS 64                 // rows per tile
#define NV (ROWS * COLS / 4)    // 1872 float4 per tile (29,952 B)
#define NVPAD 2048              // padded to 8*256 -> uniform 8 issues/wave
#define PSTR 21                 // partial stride (odd -> bank-conflict-free)
#define GRID 512                // 2 blocks/CU * 256 CU; 16384 tiles = 32 iters

#define VM_WAIT8() asm volatile("s_waitcnt vmcnt(8)" ::: "memory")
#define VM_WAIT0() asm volatile("s_waitcnt vmcnt(0)" ::: "memory")
#define LGKM0()    asm volatile("s_waitcnt lgkmcnt(0)" ::: "memory")
#define RAW_BAR()                          \
  do {                                     \
    __builtin_amdgcn_sched_barrier(0);     \
    __builtin_amdgcn_s_barrier();          \
    __builtin_amdgcn_sched_barrier(0);     \
  } while (0)

// requant: y = x*m (fp32 round), y += off (fp32 round), trunc toward zero to
// int64, arithmetic >> s, clamp [0,255]. Matches jnp reference exactly.
__device__ __forceinline__ float requant(float x, float m, float off, int s) {
  float y = __fmul_rn(x, m);
  y = __fadd_rn(y, off);
  long long yi = (long long)y;
  yi >>= s;
  float r = (float)yi;
  return fminf(fmaxf(r, 0.0f), 255.0f);
}

// Transpose W1 [20,117] -> W1T [117,20]: weights for a given k contiguous.
__global__ void transpose_w1(const float* __restrict__ W1, float* __restrict__ w1t) {
  for (int idx = threadIdx.x; idx < NOUT1 * COLS; idx += blockDim.x) {
    int o = idx / COLS, k = idx % COLS;
    w1t[k * NOUT1 + o] = W1[idx];
  }
}

// Issue exactly 8 global_load_lds per wave (full exec): 7 full sweeps + a
// padded 8th whose out-of-tile lanes read src[0] and land in LDS pad
// [1872..2048). Uniform count -> uniform vmcnt(8) across waves.
__device__ __forceinline__ void stage_tile(float4* dst, const float4* src, int t) {
#pragma unroll
  for (int i = 0; i < 7; ++i)
    __builtin_amdgcn_global_load_lds(
        (const __attribute__((address_space(1))) void*)(src + t + i * 256),
        (__attribute__((address_space(3))) void*)(dst + t + i * 256), 16, 0, 0);
  const int i8 = t + 7 * 256;                    // 1792..2047
  const float4* s8 = src + (i8 < NV ? i8 : 0);   // per-lane global addr ok
  __builtin_amdgcn_global_load_lds(
      (const __attribute__((address_space(1))) void*)s8,
      (__attribute__((address_space(3))) void*)(dst + i8), 16, 0, 0);
}

// Persistent counted-vmcnt pipeline (T3/T4 minimum form). Per iteration:
//   (a) issue 8 global_load_lds -> buf[cur^1]   (next tile, stays in flight)
//   (b) s_waitcnt vmcnt(8)  -- retires everything EXCEPT the 8 just issued:
//       all of tile-cur's loads + any older output stores. Never drains the
//       prefetch (the R3 mistake via __syncthreads).
//   (c) raw s_barrier -> buf[cur] visible to all waves
//   (d) k-loop on buf[cur]; (e) 2-stage partial merge in P (lgkmcnt(0)-only
//       barriers); (f) fused tail + store.
// Hazards: buf[cur^1] overwrite fenced by prev iter's b1+b2 (all waves past
// their k-loop reads); P reuse fenced by (c). Last iter waits vmcnt(0).
template <bool TW>
__global__ __launch_bounds__(256, 2) void fann_pipe(
    const float* __restrict__ X, const float* __restrict__ W1,
    const float* __restrict__ b1, const float* __restrict__ W2,
    const float* __restrict__ b2, float* __restrict__ out, int ntiles) {
  __shared__ __align__(16) float4 buf[2][NVPAD];   // 65,536 B
  __shared__ float P[2][ROWS * PSTR];              // 10,752 B -> 2 blocks/CU
  const int t = threadIdx.x;
  const int w = __builtin_amdgcn_readfirstlane(t >> 6);
  const int l = t & 63;
  const int k0 = w * 29;
  const int kn = (w == 3) ? 30 : 29;   // wave-uniform trip count
  const int G = gridDim.x;
  const float4* __restrict__ Xv = reinterpret_cast<const float4*>(X);

  int tile = blockIdx.x;
  int cur = 0;
  if (tile < ntiles) stage_tile(buf[0], Xv + (size_t)tile * NV, t);

  for (; tile < ntiles; tile += G, cur ^= 1) {
    const int nt = tile + G;
    const bool pf = (nt < ntiles);
    if (pf) stage_tile(buf[cur ^ 1], Xv + (size_t)nt * NV, t);
    if (pf) VM_WAIT8(); else VM_WAIT0();
    RAW_BAR();  // (c): buf[cur] staged everywhere; P free for this iter

    // ---- layer-1 k-loop on buf[cur] ----
    float acc[NOUT1];
#pragma unroll
    for (int o = 0; o < NOUT1; ++o) acc[o] = 0.0f;
    const float* xr = (const float*)buf[cur] + l * COLS + k0;  // stride 117
    if (TW) {
      const float4* __restrict__ w4 =
          reinterpret_cast<const float4*>(W1) + (size_t)k0 * (NOUT1 / 4);
      for (int kk = 0; kk < kn; ++kk) {
        float x = xr[kk];
#pragma unroll
        for (int j = 0; j < 5; ++j) {
          float4 wv = w4[kk * 5 + j];  // uniform address -> s_load
          acc[4 * j + 0] = fmaf(x, wv.x, acc[4 * j + 0]);
          acc[4 * j + 1] = fmaf(x, wv.y, acc[4 * j + 1]);
          acc[4 * j + 2] = fmaf(x, wv.z, acc[4 * j + 2]);
          acc[4 * j + 3] = fmaf(x, wv.w, acc[4 * j + 3]);
        }
      }
    } else {
      for (int kk = 0; kk < kn; ++kk) {
        float x = xr[kk];
#pragma unroll
        for (int o = 0; o < NOUT1; ++o)
          acc[o] = fmaf(x, W1[o * COLS + k0 + kk], acc[o]);
      }
    }

    // ---- 2-stage 4-wave partial merge into P[2][64][21] ----
    if (w < 2) {  // stage A: waves 0,1 write
      float* pw = P[w] + l * PSTR;
#pragma unroll
      for (int o = 0; o < NOUT1; ++o) pw[o] = acc[o];
    }
    LGKM0();
    RAW_BAR();    // b1
    if (w >= 2) {  // stage B: waves 2,3 add into region w-2 (exclusive owner)
      float* pw = P[w - 2] + l * PSTR;
#pragma unroll
      for (int o = 0; o < NOUT1; ++o) pw[o] += acc[o];
    }
    LGKM0();
    RAW_BAR();    // b2: merged partials visible

    // ---- fused tail: lane l -> row r = 16w+(l&15), out-group og = l>>4 ----
    {
      const int r = (w << 4) + (l & 15);
      const int og = l >> 4;
      float g0 = 0.0f, g1 = 0.0f;
#pragma unroll
      for (int j = 0; j < 5; ++j) {
        const int o = og * 5 + j;
        float h = P[0][r * PSTR + o] + P[1][r * PSTR + o];
        h += b1[o];
        float hq = requant(h, 1565.0f, 16384.0f, 15);
        g0 = fmaf(hq, W2[o], g0);
        g1 = fmaf(hq, W2[NOUT1 + o], g1);
      }
      const int lb = l & 15;
      float a01 = __shfl(g0, lb + 16);
      float a02 = __shfl(g0, lb + 32);
      float a03 = __shfl(g0, lb + 48);
      float a11 = __shfl(g1, lb + 16);
      float a12 = __shfl(g1, lb + 32);
      float a13 = __shfl(g1, lb + 48);
      if (og == 0) {
        float s0 = ((g0 + a01) + a02) + a03 + b2[0];
        float s1 = ((g1 + a11) + a12) + a13 + b2[1];
        float2 res;
        res.x = requant(s0, 1342.0f, 16384.0f, 15);
        res.y = requant(s1, 1342.0f, 16384.0f, 15);
        reinterpret_cast<float2*>(out)[(size_t)tile * ROWS + r] = res;
      }
    }
  }
}

// Tail for row counts not divisible by ROWS (not hit for B=1048576).
__global__ void fann_tail(const float* __restrict__ X, const float* __restrict__ W1,
                          const float* __restrict__ b1, const float* __restrict__ W2,
                          const float* __restrict__ b2, float* __restrict__ out,
                          int start, int B) {
  int row = start + blockIdx.x * blockDim.x + threadIdx.x;
  if (row >= B) return;
  float acc[NOUT1];
#pragma unroll
  for (int o = 0; o < NOUT1; ++o) acc[o] = b1[o];
  const float* xr = X + (size_t)row * COLS;
  for (int k = 0; k < COLS; ++k) {
    float x = xr[k];
#pragma unroll
    for (int o = 0; o < NOUT1; ++o) acc[o] = fmaf(x, W1[o * COLS + k], acc[o]);
  }
  float s0 = b2[0], s1 = b2[1];
#pragma unroll
  for (int o = 0; o < NOUT1; ++o) {
    float hq = requant(acc[o], 1565.0f, 16384.0f, 15);
    s0 = fmaf(hq, W2[o], s0);
    s1 = fmaf(hq, W2[NOUT1 + o], s1);
  }
  out[(size_t)row * 2 + 0] = requant(s0, 1342.0f, 16384.0f, 15);
  out[(size_t)row * 2 + 1] = requant(s1, 1342.0f, 16384.0f, 15);
}

extern "C" void kernel_launch(void* const* d_in, const int* in_sizes, int n_in,
                              void* d_out, int out_size, void* d_ws, size_t ws_size,
                              hipStream_t stream) {
  const float* X  = (const float*)d_in[0];
  const float* W1 = (const float*)d_in[1];
  const float* b1 = (const float*)d_in[2];
  const float* W2 = (const float*)d_in[3];
  const float* b2 = (const float*)d_in[4];
  float* out = (float*)d_out;
  const int B = in_sizes[0] / COLS;
  const int ntiles = B / ROWS;
  const int tail = B - ntiles * ROWS;
  const int grid = (ntiles < GRID) ? (ntiles > 0 ? ntiles : 1) : GRID;

  const bool useT = ws_size >= (size_t)(COLS * NOUT1 * sizeof(float));
  if (useT) {
    float* w1t = (float*)d_ws;
    transpose_w1<<<1, 256, 0, stream>>>(W1, w1t);
    if (ntiles > 0)
      fann_pipe<true><<<grid, 256, 0, stream>>>(X, w1t, b1, W2, b2, out, ntiles);
  } else {
    if (ntiles > 0)
      fann_pipe<false><<<grid, 256, 0, stream>>>(X, W1, b1, W2, b2, out, ntiles);
  }
  if (tail > 0)
    fann_tail<<<(tail + 63) / 64, 64, 0, stream>>>(X, W1, b1, W2, b2, out,
                                                   ntiles * ROWS, B);
}

// Round 10
// 111.263 us; speedup vs baseline: 1.4667x; 1.4667x over previous
//
#include <hip/hip_runtime.h>

#define COLS 117
#define NOUT1 20
#define ROWS 64                // rows per block (= wave width, 1 lane/row)
#define NV (ROWS * COLS / 4)   // 1872 float4 per tile
#define REM (NV - 7 * 256)     // 80 leftover float4 after 7 full sweeps
#define PSTR 21                // padded partial stride (odd -> conflict-free)
#define PFROW (ROWS * PSTR)    // 1344

// requant: y = x*m (fp32 round), y += off (fp32 round), trunc toward zero to
// int64, arithmetic >> s, clamp [0,255]. Matches jnp reference exactly.
__device__ __forceinline__ float requant(float x, float m, float off, int s) {
  float y = __fmul_rn(x, m);
  y = __fadd_rn(y, off);
  long long yi = (long long)y;   // trunc toward zero, like astype(int64)
  yi >>= s;                      // arithmetic shift
  float r = (float)yi;
  return fminf(fmaxf(r, 0.0f), 255.0f);
}

// Transpose W1 [20,117] -> W1T [117,20]: weights for a given k contiguous.
__global__ void transpose_w1(const float* __restrict__ W1, float* __restrict__ w1t) {
  for (int idx = threadIdx.x; idx < NOUT1 * COLS; idx += blockDim.x) {
    int o = idx / COLS, k = idx % COLS;
    w1t[k * NOUT1 + o] = W1[idx];
  }
}

// R8 structure (110.7 us) + first-round convoy-breaking stagger.
// Convoy theory: co-resident blocks on a CU have identical deterministic
// durations -> stage bursts phase-lock -> memory pipe idles during the
// synchronized compute phases, and the lock never decays. De-phasing the
// FIRST occupancy round (blockIdx < 1280 = 5 blocks/CU x 256 CU) by
// ~2880 cyc per phase step staggers every subsequent round for free.
template <bool TW>
__global__ __launch_bounds__(256, 5) void fann_kernel(
    const float* __restrict__ X, const float* __restrict__ W1,
    const float* __restrict__ b1, const float* __restrict__ W2,
    const float* __restrict__ b2, float* __restrict__ out) {
  __shared__ __align__(16) float xs[ROWS * COLS];  // 29,952 B -> 5 blocks/CU
  float4* xs4 = (float4*)xs;
  const int t = threadIdx.x;

  // --- convoy-breaking stagger (first round only; output-invariant) ---
  if (blockIdx.x < 1280) {
    const int phase = (blockIdx.x >> 8) % 5;  // co-resident ids differ by 256
    for (int i = 0; i < phase; ++i) __builtin_amdgcn_s_sleep(45);  // ~2880 cyc
  }

  {
    const float4* __restrict__ src =
        reinterpret_cast<const float4*>(X) + (size_t)blockIdx.x * NV;
    // Direct global->LDS DMA; dest linear = lane-order rule (m104).
    #pragma unroll
    for (int i = 0; i < 7; ++i)
      __builtin_amdgcn_global_load_lds(
          (const __attribute__((address_space(1))) void*)&src[t + i * 256],
          (__attribute__((address_space(3))) void*)&xs4[t + i * 256], 16, 0, 0);
    if (t < REM)
      __builtin_amdgcn_global_load_lds(
          (const __attribute__((address_space(1))) void*)&src[t + 7 * 256],
          (__attribute__((address_space(3))) void*)&xs4[t + 7 * 256], 16, 0, 0);
  }
  __syncthreads();  // #0: tile staged (drains vmcnt)

  const int w = __builtin_amdgcn_readfirstlane(t >> 6);  // wave id in SGPR
  const int l = t & 63;                                  // row within tile
  const int k0 = w * 29;
  const int kn = (w == 3) ? 30 : 29;   // wave-uniform trip count

  float acc[NOUT1];
  #pragma unroll
  for (int o = 0; o < NOUT1; ++o) acc[o] = 0.0f;
  const float* xr = xs + l * COLS + k0;  // lane stride 117 (odd) -> free

  if (TW) {
    const float4* __restrict__ w4 =
        reinterpret_cast<const float4*>(W1) + (size_t)k0 * (NOUT1 / 4);
    for (int kk = 0; kk < kn; ++kk) {
      float x = xr[kk];
      #pragma unroll
      for (int j = 0; j < 5; ++j) {
        float4 wv = w4[kk * 5 + j];   // uniform address -> s_load
        acc[4 * j + 0] = fmaf(x, wv.x, acc[4 * j + 0]);
        acc[4 * j + 1] = fmaf(x, wv.y, acc[4 * j + 1]);
        acc[4 * j + 2] = fmaf(x, wv.z, acc[4 * j + 2]);
        acc[4 * j + 3] = fmaf(x, wv.w, acc[4 * j + 3]);
      }
    }
  } else {
    for (int kk = 0; kk < kn; ++kk) {
      float x = xr[kk];
      #pragma unroll
      for (int o = 0; o < NOUT1; ++o)
        acc[o] = fmaf(x, W1[o * COLS + k0 + kk], acc[o]);
    }
  }
  __syncthreads();  // #1: all x reads of xs done -> safe to overwrite

  {  // partials A[w][row][o], stride 21 (odd) -> conflict-free
    float* pw = xs + w * PFROW + l * PSTR;
    #pragma unroll
    for (int o = 0; o < NOUT1; ++o) pw[o] = acc[o];
  }
  __syncthreads();  // #2: partials visible

  // Fused tail, all 256 lanes busy. Wave w owns rows 16w..16w+15; lane l:
  // row r = 16w + (l&15), output-group og = l>>4 covers outputs 5og..5og+4.
  {
    const int r  = (w << 4) + (l & 15);
    const int og = l >> 4;
    float g0 = 0.0f, g1 = 0.0f;
    #pragma unroll
    for (int j = 0; j < 5; ++j) {
      const int o = og * 5 + j;
      const float* pa = xs + r * PSTR + o;
      float h = pa[0 * PFROW] + pa[1 * PFROW] + pa[2 * PFROW] + pa[3 * PFROW];
      h += b1[o];
      float hq = requant(h, 1565.0f, 16384.0f, 15);
      g0 = fmaf(hq, W2[o], g0);
      g1 = fmaf(hq, W2[NOUT1 + o], g1);
    }
    const int lb = l & 15;
    float a01 = __shfl(g0, lb + 16);
    float a02 = __shfl(g0, lb + 32);
    float a03 = __shfl(g0, lb + 48);
    float a11 = __shfl(g1, lb + 16);
    float a12 = __shfl(g1, lb + 32);
    float a13 = __shfl(g1, lb + 48);
    if (og == 0) {
      float s0 = ((g0 + a01) + a02) + a03 + b2[0];
      float s1 = ((g1 + a11) + a12) + a13 + b2[1];
      float2 res;
      res.x = requant(s0, 1342.0f, 16384.0f, 15);
      res.y = requant(s1, 1342.0f, 16384.0f, 15);
      reinterpret_cast<float2*>(out)[(size_t)blockIdx.x * ROWS + r] = res;
    }
  }
}

// Tail for row counts not divisible by ROWS (not hit for B=1048576).
__global__ void fann_tail(const float* __restrict__ X, const float* __restrict__ W1,
                          const float* __restrict__ b1, const float* __restrict__ W2,
                          const float* __restrict__ b2, float* __restrict__ out,
                          int start, int B) {
  int row = start + blockIdx.x * blockDim.x + threadIdx.x;
  if (row >= B) return;
  float acc[NOUT1];
  #pragma unroll
  for (int o = 0; o < NOUT1; ++o) acc[o] = b1[o];
  const float* xr = X + (size_t)row * COLS;
  for (int k = 0; k < COLS; ++k) {
    float x = xr[k];
    #pragma unroll
    for (int o = 0; o < NOUT1; ++o) acc[o] = fmaf(x, W1[o * COLS + k], acc[o]);
  }
  float s0 = b2[0], s1 = b2[1];
  #pragma unroll
  for (int o = 0; o < NOUT1; ++o) {
    float hq = requant(acc[o], 1565.0f, 16384.0f, 15);
    s0 = fmaf(hq, W2[o], s0);
    s1 = fmaf(hq, W2[NOUT1 + o], s1);
  }
  out[(size_t)row * 2 + 0] = requant(s0, 1342.0f, 16384.0f, 15);
  out[(size_t)row * 2 + 1] = requant(s1, 1342.0f, 16384.0f, 15);
}

extern "C" void kernel_launch(void* const* d_in, const int* in_sizes, int n_in,
                              void* d_out, int out_size, void* d_ws, size_t ws_size,
                              hipStream_t stream) {
  const float* X  = (const float*)d_in[0];
  const float* W1 = (const float*)d_in[1];
  const float* b1 = (const float*)d_in[2];
  const float* W2 = (const float*)d_in[3];
  const float* b2 = (const float*)d_in[4];
  float* out = (float*)d_out;
  const int B = in_sizes[0] / COLS;
  const int nblk = B / ROWS;
  const int tail = B - nblk * ROWS;

  const bool useT = ws_size >= (size_t)(COLS * NOUT1 * sizeof(float));
  if (useT) {
    float* w1t = (float*)d_ws;
    transpose_w1<<<1, 256, 0, stream>>>(W1, w1t);
    if (nblk > 0)
      fann_kernel<true><<<nblk, 256, 0, stream>>>(X, w1t, b1, W2, b2, out);
  } else {
    if (nblk > 0)
      fann_kernel<false><<<nblk, 256, 0, stream>>>(X, W1, b1, W2, b2, out);
  }
  if (tail > 0)
    fann_tail<<<(tail + 63) / 64, 64, 0, stream>>>(X, W1, b1, W2, b2, out,
                                                   nblk * ROWS, B);
}